// Round 4
// baseline (394.821 us; speedup 1.0000x reference)
//
#include <hip/hip_runtime.h>
#include <hip/hip_bf16.h>

typedef __bf16 bf16;
typedef __bf16 bf16x8 __attribute__((ext_vector_type(8)));
typedef float  f32x4  __attribute__((ext_vector_type(4)));

// ---------------------------------------------------------------------------
// NNConv, node-centric restructure (round 4):
//   Rounds 0-3: every per-edge-tile structure pinned at ~85us/edge-kernel
//   (atomic-bound, then random-HBM-bound, then store/gather-latency-bound).
//   Fix: aggregation commutes with the GEMM:
//     agg[v] = U[v] @ Wflat + S[v] @ bbmat,
//     U[v][j,i] = sum_{e->v} he[e][j] * x[src_e][i],  S[v] = sum x[src_e]
//   -> edge_accum: wave-per-node over CSR rows, U in registers, ~6 issue
//      slots per edge, one coalesced bf16 store per node. No msg stream.
//   -> gemm_node: MFMA over 16-node tiles (3125 tiles vs 50000), A-rows
//      sequential (no gather), bias as extra K-slice (verified r3 layout),
//      mean+root+relu+r2 in epilogue.
// ---------------------------------------------------------------------------

static __device__ inline unsigned short bfb(float f)
{
    __bf16 h = (__bf16)f;
    unsigned short u;
    __builtin_memcpy(&u, &h, 2);
    return u;
}

// ---------------- CSR build (unchanged, verified) ---------------------------

__global__ void hist_deg(const int* __restrict__ eidx, int* __restrict__ deg, int E)
{
    int e = blockIdx.x * blockDim.x + threadIdx.x;
    if (e < E) atomicAdd(&deg[eidx[E + e]], 1);
}

__global__ void scan_blocks(const int* __restrict__ deg, int* __restrict__ part,
                            int* __restrict__ bsum, int N)
{
    __shared__ int sm[256];
    const int t = threadIdx.x;
    const int i = blockIdx.x * 256 + t;
    int v = (i < N) ? deg[i] : 0;
    sm[t] = v;
    __syncthreads();
#pragma unroll
    for (int ofs = 1; ofs < 256; ofs <<= 1) {
        int add = (t >= ofs) ? sm[t - ofs] : 0;
        __syncthreads();
        sm[t] += add;
        __syncthreads();
    }
    if (i < N) part[i] = sm[t] - v;          // exclusive
    if (t == 255) bsum[blockIdx.x] = sm[255];
}

__global__ void scan_top(const int* __restrict__ bsum, int* __restrict__ boff, int nb)
{
    __shared__ int sm[256];
    const int t = threadIdx.x;
    int v = (t < nb) ? bsum[t] : 0;
    sm[t] = v;
    __syncthreads();
#pragma unroll
    for (int ofs = 1; ofs < 256; ofs <<= 1) {
        int add = (t >= ofs) ? sm[t - ofs] : 0;
        __syncthreads();
        sm[t] += add;
        __syncthreads();
    }
    if (t < nb) boff[t] = sm[t] - v;
}

__global__ void scan_fix(int* __restrict__ rowptr, int* __restrict__ cursor,
                         const int* __restrict__ boff, int N, int E)
{
    int i = blockIdx.x * 256 + threadIdx.x;
    if (i < N) {
        int r = rowptr[i] + boff[blockIdx.x];
        rowptr[i] = r;
        cursor[i] = r;
    }
    if (i == N) rowptr[N] = E;
}

__global__ void scatter_edges(const int* __restrict__ eidx, const float* __restrict__ ea,
                              int* __restrict__ cursor, int2* __restrict__ edat, int E)
{
    int e = blockIdx.x * blockDim.x + threadIdx.x;
    if (e >= E) return;
    int d = eidx[E + e];
    int j = atomicAdd(&cursor[d], 1);
    edat[j] = make_int2(eidx[e], __float_as_int(ea[e]));
}

// ---------------- node precompute ------------------------------------------

__global__ void node_pre1(const float* __restrict__ x,
                          const float* __restrict__ root1,
                          const float* __restrict__ bias1,
                          float* __restrict__ r1, int N)
{
    int t = blockIdx.x * blockDim.x + threadIdx.x;
    int v = t >> 4, o = t & 15;
    if (v >= N) return;
    float racc = 0.f;
#pragma unroll
    for (int i = 0; i < 8; ++i)
        racc += x[v * 8 + i] * root1[i * 16 + o];
    r1[v * 16 + o] = racc + bias1[o];
}

// ---------------- layer 1: edge accumulation (wave per node) ---------------
// Lane l owns U[j][i] for j = l>>2, i = (l&3)*2 + {0,1}.
// U row layout: elem k = j*8+i (bf16), 256 B/node. S row: 8 bf16, 16 B/node.
__global__ void edge_accum1(const float* __restrict__ x,
                            const long long* __restrict__ edat,
                            const int* __restrict__ rowptr,
                            const float* __restrict__ W_e1a,
                            const float* __restrict__ b_e1a,
                            char* __restrict__ U1, char* __restrict__ S1, int N)
{
    const int lane = threadIdx.x & 63;
    const int wave   = blockIdx.x * (blockDim.x >> 6) + (threadIdx.x >> 6);
    const int nwaves = gridDim.x * (blockDim.x >> 6);
    const int j  = lane >> 2;
    const int ip = (lane & 3) * 2;

    const float wa = W_e1a[j];
    const float bb = b_e1a[j];

    for (int v = wave; v < N; v += nwaves) {
        const int t0 = rowptr[v], t1 = rowptr[v + 1];
        float u0 = 0.f, u1 = 0.f, s0 = 0.f, s1 = 0.f;
        for (int t = t0; t < t1; ++t) {
            long long ed = edat[t];                     // wave-uniform
            int   s   = (int)(ed & 0xffffffffLL);
            float eav = __int_as_float((int)(ed >> 32));
            float he  = wa * eav + bb;
            he = he > 0.f ? he : 0.f;
            float2 xv = *(const float2*)(x + (size_t)s * 8 + ip);
            u0 += he * xv.x;
            u1 += he * xv.y;
            s0 += xv.x;
            s1 += xv.y;
        }
        unsigned up = (unsigned)bfb(u0) | ((unsigned)bfb(u1) << 16);
        *(unsigned*)(U1 + (size_t)v * 256 + j * 16 + (lane & 3) * 4) = up;
        if (lane < 4) {
            unsigned sp = (unsigned)bfb(s0) | ((unsigned)bfb(s1) << 16);
            *(unsigned*)(S1 + (size_t)v * 16 + (lane & 3) * 4) = sp;
        }
    }
}

// ---------------- layer 1: node GEMM (16 nodes/tile, K=128 + bias slice) ---
__global__ void gemm_node1(const char* __restrict__ U1, const char* __restrict__ S1,
                           const int* __restrict__ deg, const float* __restrict__ r1,
                           const float* __restrict__ W_e1b, const float* __restrict__ b_e1b,
                           const float* __restrict__ root2, const float* __restrict__ bias2,
                           float* __restrict__ h1, float* __restrict__ r2,
                           int N, int ntiles)
{
    const int lane = threadIdx.x & 63;
    const int m = lane & 15;          // A row (node in tile) / C col (out chan)
    const int q = lane >> 4;
    const int wave   = blockIdx.x * (blockDim.x >> 6) + (threadIdx.x >> 6);
    const int nwaves = gridDim.x * (blockDim.x >> 6);

    // B fragments (round-3 verified): B[k][n] = W_e1b[(i*16+n)*16+j], j=c*4+q, i=t
    bf16x8 bfrag[4];
#pragma unroll
    for (int c = 0; c < 4; ++c)
#pragma unroll
        for (int t = 0; t < 8; ++t)
            bfrag[c][t] = (bf16)W_e1b[(t * 16 + m) * 16 + (c * 4 + q)];

    // bias slice (round-3 verified): active only on q==0 k-slots
    bf16x8 bfragb;
#pragma unroll
    for (int t = 0; t < 8; ++t)
        bfragb[t] = (q == 0) ? (bf16)b_e1b[t * 16 + m] : (bf16)0.f;

    // epilogue constants: root2 column m
    float rt[16];
#pragma unroll
    for (int i = 0; i < 16; ++i) rt[i] = root2[i * 16 + m];
    const float b2 = bias2[m];

    for (int tile = wave; tile < ntiles; tile += nwaves) {
        const int v = tile * 16 + m;
        const char* arow = U1 + (size_t)v * 256;

        f32x4 acc = {0.f, 0.f, 0.f, 0.f};

        // bias K-slice: A = S[v] (broadcast across q; B zero for q!=0)
        bf16x8 afs = *(const bf16x8*)(S1 + (size_t)v * 16);
        acc = __builtin_amdgcn_mfma_f32_16x16x32_bf16(afs, bfragb, acc, 0, 0, 0);

#pragma unroll
        for (int c = 0; c < 4; ++c) {
            bf16x8 af = *(const bf16x8*)(arow + c * 64 + q * 16);
            acc = __builtin_amdgcn_mfma_f32_16x16x32_bf16(af, bfrag[c], acc, 0, 0, 0);
        }

        // epilogue: mean + root + relu, then r2 = h @ root2 + bias2
#pragma unroll
        for (int reg = 0; reg < 4; ++reg) {
            int vr = tile * 16 + q * 4 + reg;
            int vc = vr < N ? vr : N - 1;
            float c = (float)deg[vc]; c = c > 1.f ? c : 1.f;
            float h = acc[reg] / c + r1[(size_t)vc * 16 + m];
            h = h > 0.f ? h : 0.f;
            float racc = b2;
#pragma unroll
            for (int i = 0; i < 16; ++i)
                racc += __shfl(h, i, 16) * rt[i];
            if (vr < N) {
                h1[(size_t)vr * 16 + m] = h;
                r2[(size_t)vr * 16 + m] = racc;
            }
        }
    }
}

// ---------------- layer 2: edge accumulation (wave per node) ---------------
// Lane l owns U2[j][i] for j = l>>2, i = (l&3)*4 + {0..3}.
// U2 row: elem k = j*16+i (bf16), 512 B/node. S2 row: 16 bf16, 32 B/node.
__global__ void edge_accum2(const float* __restrict__ h1g,
                            const long long* __restrict__ edat,
                            const int* __restrict__ rowptr,
                            const float* __restrict__ W_e2a,
                            const float* __restrict__ b_e2a,
                            char* __restrict__ U2, char* __restrict__ S2, int N)
{
    const int lane = threadIdx.x & 63;
    const int wave   = blockIdx.x * (blockDim.x >> 6) + (threadIdx.x >> 6);
    const int nwaves = gridDim.x * (blockDim.x >> 6);
    const int j  = lane >> 2;
    const int ip = (lane & 3) * 4;

    const float wa = W_e2a[j];
    const float bb = b_e2a[j];

    for (int v = wave; v < N; v += nwaves) {
        const int t0 = rowptr[v], t1 = rowptr[v + 1];
        float u0 = 0.f, u1 = 0.f, u2 = 0.f, u3 = 0.f;
        float s0 = 0.f, s1 = 0.f, s2 = 0.f, s3 = 0.f;
        for (int t = t0; t < t1; ++t) {
            long long ed = edat[t];                     // wave-uniform
            int   s   = (int)(ed & 0xffffffffLL);
            float eav = __int_as_float((int)(ed >> 32));
            float he  = wa * eav + bb;
            he = he > 0.f ? he : 0.f;
            float4 hv = *(const float4*)(h1g + (size_t)s * 16 + ip);
            u0 += he * hv.x;  u1 += he * hv.y;
            u2 += he * hv.z;  u3 += he * hv.w;
            s0 += hv.x;  s1 += hv.y;  s2 += hv.z;  s3 += hv.w;
        }
        uint2 up;
        up.x = (unsigned)bfb(u0) | ((unsigned)bfb(u1) << 16);
        up.y = (unsigned)bfb(u2) | ((unsigned)bfb(u3) << 16);
        *(uint2*)(U2 + (size_t)v * 512 + j * 32 + (lane & 3) * 8) = up;
        if (lane < 4) {
            uint2 sp;
            sp.x = (unsigned)bfb(s0) | ((unsigned)bfb(s1) << 16);
            sp.y = (unsigned)bfb(s2) | ((unsigned)bfb(s3) << 16);
            *(uint2*)(S2 + (size_t)v * 32 + (lane & 3) * 8) = sp;
        }
    }
}

// ---------------- layer 2: node GEMM (K=256 + bias slice) ------------------
__global__ void gemm_node2(const char* __restrict__ U2, const char* __restrict__ S2,
                           const int* __restrict__ deg, const float* __restrict__ r2,
                           const float* __restrict__ W_e2b, const float* __restrict__ b_e2b,
                           float* __restrict__ out_h, int N, int ntiles)
{
    const int lane = threadIdx.x & 63;
    const int m = lane & 15;
    const int q = lane >> 4;
    const int qh = q >> 1;            // j = 2c + qh
    const int ql = q & 1;             // i = ql*8 + t
    const int wave   = blockIdx.x * (blockDim.x >> 6) + (threadIdx.x >> 6);
    const int nwaves = gridDim.x * (blockDim.x >> 6);

    bf16x8 bfrag[8];
#pragma unroll
    for (int c = 0; c < 8; ++c) {
        int j = c * 2 + qh;
#pragma unroll
        for (int t = 0; t < 8; ++t) {
            int i = ql * 8 + t;
            bfrag[c][t] = (bf16)W_e2b[(i * 16 + m) * 16 + j];
        }
    }

    bf16x8 bfragb;
#pragma unroll
    for (int t = 0; t < 8; ++t)
        bfragb[t] = (qh == 0) ? (bf16)b_e2b[(ql * 8 + t) * 16 + m] : (bf16)0.f;

    for (int tile = wave; tile < ntiles; tile += nwaves) {
        const int v = tile * 16 + m;
        const char* arow = U2 + (size_t)v * 512;

        f32x4 acc = {0.f, 0.f, 0.f, 0.f};

        bf16x8 afs = *(const bf16x8*)(S2 + (size_t)v * 32 + ql * 16);
        acc = __builtin_amdgcn_mfma_f32_16x16x32_bf16(afs, bfragb, acc, 0, 0, 0);

#pragma unroll
        for (int c = 0; c < 8; ++c) {
            bf16x8 af = *(const bf16x8*)(arow + c * 64 + q * 16);
            acc = __builtin_amdgcn_mfma_f32_16x16x32_bf16(af, bfrag[c], acc, 0, 0, 0);
        }

#pragma unroll
        for (int reg = 0; reg < 4; ++reg) {
            int vr = tile * 16 + q * 4 + reg;
            if (vr < N) {
                float c = (float)deg[vr]; c = c > 1.f ? c : 1.f;
                float h = acc[reg] / c + r2[(size_t)vr * 16 + m];
                h = h > 0.f ? h : 0.f;
                out_h[(size_t)vr * 16 + m] = h;
            }
        }
    }
}

// ---------------- pooling (verified) + batch passthrough -------------------
__global__ void pool_seg(const float* __restrict__ h, const int* __restrict__ batch,
                         float* __restrict__ out_g, float* __restrict__ out_b, int N)
{
    const int b = blockIdx.x;
    int lo = 0, hi = N;
    while (lo < hi) { int mid = (lo + hi) >> 1; if (batch[mid] < b) lo = mid + 1; else hi = mid; }
    const int start = lo;
    hi = N;
    while (lo < hi) { int mid = (lo + hi) >> 1; if (batch[mid] < b + 1) lo = mid + 1; else hi = mid; }
    const int end = lo;

    const int ch = threadIdx.x & 15, grp = threadIdx.x >> 4;
    float acc = 0.f;
    for (int v = start + grp; v < end; v += 16) {
        acc += h[(size_t)v * 16 + ch];
        if (ch == 0) out_b[v] = (float)b;
    }

    __shared__ float red[256];
    red[threadIdx.x] = acc;
    __syncthreads();
#pragma unroll
    for (int s = 128; s >= 16; s >>= 1) {
        if (threadIdx.x < s) red[threadIdx.x] += red[threadIdx.x + s];
        __syncthreads();
    }
    if (threadIdx.x < 16) {
        float c = (float)(end - start); c = c > 1.f ? c : 1.f;
        out_g[b * 16 + threadIdx.x] = red[threadIdx.x] / c;
    }
}

extern "C" void kernel_launch(void* const* d_in, const int* in_sizes, int n_in,
                              void* d_out, int out_size, void* d_ws, size_t ws_size,
                              hipStream_t stream)
{
    const float* x     = (const float*)d_in[0];
    const float* ea    = (const float*)d_in[1];
    const float* W_e1a = (const float*)d_in[2];
    const float* b_e1a = (const float*)d_in[3];
    const float* W_e1b = (const float*)d_in[4];
    const float* b_e1b = (const float*)d_in[5];
    const float* root1 = (const float*)d_in[6];
    const float* bias1 = (const float*)d_in[7];
    const float* W_e2a = (const float*)d_in[8];
    const float* b_e2a = (const float*)d_in[9];
    const float* W_e2b = (const float*)d_in[10];
    const float* b_e2b = (const float*)d_in[11];
    const float* root2 = (const float*)d_in[12];
    const float* bias2 = (const float*)d_in[13];
    const int*   eidx  = (const int*)d_in[14];
    const int*   batch = (const int*)d_in[15];

    const int E  = in_sizes[1];       // 800000
    const int N  = in_sizes[15];      // 50000
    const int Bg = (out_size - N * 16 - N) / 16;   // 64

    const int ntiles = (N + 15) / 16;             // 3125
    const int npad   = ntiles * 16;

    auto align16 = [](size_t v) { return (v + 15) & ~(size_t)15; };

    char* ws = (char*)d_ws;
    size_t off = 0;
    int*   deg    = (int*)(ws + off);  off = align16(off + (size_t)N * 4);
    size_t zero_bytes = off;                     // only deg needs zeroing
    int*   rowptr = (int*)(ws + off);  off = align16(off + (size_t)(N + 1) * 4);
    int*   cursor = (int*)(ws + off);  off = align16(off + (size_t)N * 4);
    int*   bsum   = (int*)(ws + off);  off = align16(off + 256 * 4);
    int*   boff   = (int*)(ws + off);  off = align16(off + 256 * 4);
    int2*  edat   = (int2*)(ws + off); off = align16(off + (size_t)E * 8);
    char*  U1     = ws + off;          off = align16(off + (size_t)npad * 256);
    char*  S1     = ws + off;          off = align16(off + (size_t)npad * 16);
    char*  U2     = ws + off;          off = align16(off + (size_t)npad * 512);
    char*  S2     = ws + off;          off = align16(off + (size_t)npad * 32);
    float* r1     = (float*)(ws + off); off = align16(off + (size_t)N * 16 * 4);
    float* h1     = (float*)(ws + off); off = align16(off + (size_t)N * 16 * 4);
    float* r2     = (float*)(ws + off); off = align16(off + (size_t)N * 16 * 4);

    hipMemsetAsync(d_ws, 0, zero_bytes, stream);

    const int nodeBlocks = (N * 16 + 255) / 256;
    const int edgeThreadBlocks = (E + 255) / 256;
    const int scanBlocks = (N + 255) / 256;       // 196 (must be <= 256)
    const int accumBlocks = 2048;                 // 8192 waves, ~6 nodes each
    const int gemmBlocks = (ntiles + 3) / 4;      // 1 wave per tile

    // CSR build
    hist_deg<<<edgeThreadBlocks, 256, 0, stream>>>(eidx, deg, E);
    scan_blocks<<<scanBlocks, 256, 0, stream>>>(deg, rowptr, bsum, N);
    scan_top<<<1, 256, 0, stream>>>(bsum, boff, scanBlocks);
    scan_fix<<<scanBlocks, 256, 0, stream>>>(rowptr, cursor, boff, N, E);
    scatter_edges<<<edgeThreadBlocks, 256, 0, stream>>>(eidx, ea, cursor, edat, E);

    // layer 1
    node_pre1<<<nodeBlocks, 256, 0, stream>>>(x, root1, bias1, r1, N);
    edge_accum1<<<accumBlocks, 256, 0, stream>>>(x, (const long long*)edat, rowptr,
                                                 W_e1a, b_e1a, U1, S1, N);
    gemm_node1<<<gemmBlocks, 256, 0, stream>>>(U1, S1, deg, r1, W_e1b, b_e1b,
                                               root2, bias2, h1, r2, N, ntiles);

    // layer 2
    edge_accum2<<<accumBlocks, 256, 0, stream>>>(h1, (const long long*)edat, rowptr,
                                                 W_e2a, b_e2a, U2, S2, N);

    float* out_h = (float*)d_out;
    float* out_g = out_h + (size_t)N * 16;
    float* out_b = out_g + (size_t)Bg * 16;
    gemm_node2<<<gemmBlocks, 256, 0, stream>>>(U2, S2, deg, r2, W_e2b, b_e2b,
                                               out_h, N, ntiles);
    pool_seg<<<Bg, 256, 0, stream>>>(out_h, batch, out_g, out_b, N);
}